// Round 7
// baseline (86.385 us; speedup 1.0000x reference)
//
#include <hip/hip_runtime.h>
#include <hip/hip_bf16.h>

typedef __attribute__((ext_vector_type(8))) short short8;
typedef __attribute__((ext_vector_type(4))) float f32x4;

#define NC    91
#define DM    64
#define CIN   128
#define NMOV  4206
#define MR    96      // row-padded (6 x 16)
#define HP    68      // hbuf fp32 pitch
#define SP    100     // S fp32 pitch (400B/row; P bf16 aliases first 256B via swizzle)
#define GP    96      // gram fp32 pitch
#define NT    1024
#define NW    16

__constant__ int HEXOFF[NC] = {
  55,66,77,88,99,110,
  45,56,67,78,89,100,111,
  35,46,57,68,79,90,101,112,
  25,36,47,58,69,80,91,102,113,
  15,26,37,48,59,70,81,92,103,114,
  5,16,27,38,49,60,71,82,93,104,115,
  6,17,28,39,50,61,72,83,94,105,
  7,18,29,40,51,62,73,84,95,
  8,19,30,41,52,63,74,85,
  9,20,31,42,53,64,75,
  10,21,32,43,54,65
};

// byte offset into a bf16 buffer with PB bytes/row; 16B-slot XOR swizzle by row&7
#define SWZ(row, col, PB) ((row)*(PB) + ((((((col)*2)>>4)) ^ ((row)&7)) << 4) + (((col)*2)&15))

__device__ __forceinline__ short f2bf(float f) {
  __hip_bfloat16 h = __float2bfloat16(f);
  return __builtin_bit_cast(short, h);
}

__device__ __forceinline__ short8 ldfrag128(const short* buf, int row, int k0) {
  return *(const short8*)((const char*)buf + SWZ(row, k0, 128));
}
__device__ __forceinline__ short8 ldfrag256(const short* buf, int row, int k0) {
  return *(const short8*)((const char*)buf + SWZ(row, k0, 256));
}
__device__ __forceinline__ void stb16_128(short* buf, int row, int col, float v) {
  *(short*)((char*)buf + SWZ(row, col, 128)) = f2bf(v);
}

// stage 8 consecutive floats (col multiple of 8) as one swizzled 16B bf16 store
__device__ __forceinline__ void stg8(short* buf, int row, int col, const float* src, int PB) {
  float4 f0 = *(const float4*)(src);
  float4 f1 = *(const float4*)(src + 4);
  short8 v;
  v[0]=f2bf(f0.x); v[1]=f2bf(f0.y); v[2]=f2bf(f0.z); v[3]=f2bf(f0.w);
  v[4]=f2bf(f1.x); v[5]=f2bf(f1.y); v[6]=f2bf(f1.z); v[7]=f2bf(f1.w);
  *(short8*)((char*)buf + (row)*(PB) + (((((col)*2)>>4) ^ ((row)&7)) << 4)) = v;
}

__global__ __launch_bounds__(1024, 1)
void policy_fused(
    const float* __restrict__ x,
    const float* __restrict__ embed_w, const float* __restrict__ embed_b,
    const float* __restrict__ pos,
    const float* __restrict__ in_w,  const float* __restrict__ in_b,
    const float* __restrict__ out_w, const float* __restrict__ out_b,
    const float* __restrict__ ln1_g, const float* __restrict__ ln1_b,
    const float* __restrict__ ln2_g, const float* __restrict__ ln2_b,
    const float* __restrict__ ff1_w, const float* __restrict__ ff1_b,
    const float* __restrict__ ff2_w, const float* __restrict__ ff2_b,
    const float* __restrict__ from_w, const float* __restrict__ from_b,
    const float* __restrict__ to_w,  const float* __restrict__ to_b,
    const float* __restrict__ move_bias,
    const int* __restrict__ move_from, const int* __restrict__ move_to,
    float* __restrict__ out)
{
  __shared__ float hbuf[MR*HP];      // residual h fp32                    26112 B
  __shared__ float r1f[9600];        // feats(bf16) / S+P / G              38400 B
  __shared__ float r2f[9856];        // qb,kb,vtb,linv / f1 / F,T          39424 B
  __shared__ short ab16[MR*64];      // bf16 A-staging (swz, PB=128)       12288 B
  __shared__ short wA[192*64];       // weights bf16 (swz, PB=128)         24576 B
  __shared__ short wB[64*128];       // weights bf16 (swz, PB=256)         16384 B

  const int tid  = threadIdx.x;
  const int lane = tid & 63;
  const int wid  = tid >> 6;
  const int l15  = lane & 15;
  const int kfr  = (lane >> 4) * 8;   // k offset within a 32-wide k-chunk
  const int mfr  = (lane >> 4) * 4;   // C-frag row offset
  const int b    = blockIdx.x;
  const float* xb = x + (size_t)b * (CIN*121);

  short* featsb = (short*)r1f;                   // [96][128] bf16 swz PB=256
  short* qb  = (short*)r2f;                      // [4][96][16] bf16, pitch 32B
  short* kb  = qb + 6144;                        // [4][96][16]
  short* vtb = qb + 12288;                       // [4][16][104] bf16 (V^T), pitch 208B
  float* linv = r2f + 9472;                      // [4][96] fp32

  // ---- P0: hex-gather feats -> bf16 ; stage embed_w -> wB ----
  for (int e = tid; e < 16*NC; e += NT) {        // 8 channels per item
    int c0 = e / NC, i = e - c0*NC;
    float v[8];
    #pragma unroll
    for (int u = 0; u < 8; ++u) v[u] = xb[(c0*8 + u)*121 + HEXOFF[i]];
    short8 s8;
    #pragma unroll
    for (int u = 0; u < 8; ++u) s8[u] = f2bf(v[u]);
    *(short8*)((char*)featsb + i*256 + ((c0 ^ (i&7)) << 4)) = s8;
  }
  if (tid < 320) ((unsigned*)featsb)[5824 + tid] = 0;   // zero feats rows 91..95
  for (int e = tid; e < DM*CIN/8; e += NT) {     // embed_w [64][128]
    int r = e >> 4, c8 = e & 15;
    stg8(wB, r, c8*8, &embed_w[r*CIN + c8*8], 256);
  }
  __syncthreads();

  // ---- P1: embed MFMA (K=128) -> hbuf fp32 ; stage in_w -> wA ----
  for (int e = tid; e < 3*DM*DM/8; e += NT) {    // in_w [192][64]
    int r = e >> 3, c8 = e & 7;
    stg8(wA, r, c8*8, &in_w[r*DM + c8*8], 128);
  }
  for (int t = wid; t < 24; t += NW) {
    int mt = t >> 2, nt = t & 3;
    int ar = mt*16 + l15, br = nt*16 + l15;
    f32x4 acc = {0.f,0.f,0.f,0.f};
    #pragma unroll
    for (int kk = 0; kk < 4; ++kk) {
      short8 a = ldfrag256(featsb, ar, kk*32 + kfr);
      short8 w = ldfrag256(wB,      br, kk*32 + kfr);
      acc = __builtin_amdgcn_mfma_f32_16x16x32_bf16(a, w, acc, 0, 0, 0);
    }
    int col = nt*16 + l15;
    float eb = embed_b[col];
    #pragma unroll
    for (int i2 = 0; i2 < 4; ++i2) {
      int m = mt*16 + mfr + i2;
      float p = (m < NC) ? pos[m*DM + col] : 0.f;
      hbuf[m*HP + col] = acc[i2] + eb + p;
    }
  }
  __syncthreads();

  // ---- P2: LN1 -> ab16 bf16 ; stage out_w -> wB(PB=128) ; zero ab16 tail rows ----
  for (int e = tid; e < DM*DM/8; e += NT) {
    int r = e >> 3, c8 = e & 7;
    stg8((short*)wB, r, c8*8, &out_w[r*DM + c8*8], 128);
  }
  if (tid < 160) ((unsigned*)ab16)[2912 + tid] = 0;     // zero ab16 rows 91..95
  {
    const float g = ln1_g[lane], bb = ln1_b[lane];
    for (int i = wid; i < NC; i += NW) {
      float v = hbuf[i*HP + lane];
      float s = v, sq = v*v;
      #pragma unroll
      for (int off = 32; off >= 1; off >>= 1) {
        s  += __shfl_xor(s, off, 64);
        sq += __shfl_xor(sq, off, 64);
      }
      float m  = s * (1.0f/64.0f);
      float vr = sq * (1.0f/64.0f) - m*m;
      float rs = rsqrtf(vr + 1e-5f);
      stb16_128(ab16, i, lane, (v - m) * rs * g + bb);
    }
  }
  __syncthreads();

  // ---- P3: qkv MFMA (N=192, K=64) -> qb/kb bf16 head layout, vtb transposed ----
  for (int t = wid; t < 72; t += NW) {
    int mt = t / 12, nt = t - mt*12;
    int ar = mt*16 + l15, br = nt*16 + l15;
    f32x4 acc = {0.f,0.f,0.f,0.f};
    #pragma unroll
    for (int kk = 0; kk < 2; ++kk) {
      short8 a = ldfrag128(ab16, ar, kk*32 + kfr);
      short8 w = ldfrag128(wA,   br, kk*32 + kfr);
      acc = __builtin_amdgcn_mfma_f32_16x16x32_bf16(a, w, acc, 0, 0, 0);
    }
    int col = nt*16 + l15;
    float bia = in_b[col];
    int d = col & 15;
    #pragma unroll
    for (int i2 = 0; i2 < 4; ++i2) {
      int m = mt*16 + mfr + i2;
      float val = acc[i2] + bia;
      if (col < 64) {
        int h = col >> 4;
        *(short*)((char*)qb + (h*96 + m)*32 + d*2) = f2bf(val);
      } else if (col < 128) {
        int h = (col - 64) >> 4;
        *(short*)((char*)kb + (h*96 + m)*32 + d*2) = f2bf(val);
      } else {
        int h = (col - 128) >> 4;
        *(short*)((char*)vtb + (h*16 + d)*208 + m*2) = (m < NC) ? f2bf(val) : (short)0;
      }
    }
  }
  __syncthreads();

  // ---- attention: per head, QK^T MFMA -> softmax -> PV MFMA ----
  float* Sf = r1f;                                // [96][100] fp32; P bf16 aliases rows
  const short8 zfrag = {0,0,0,0,0,0,0,0};
  for (int h = 0; h < 4; ++h) {
    // A1: S = 0.25 * Q @ K^T  (K-dim 16 via zero upper fragments)
    if (h == 0) {
      for (int e = tid; e < 2*DM*DM/8; e += NT) { // stage ff1_w [128][64] -> wA
        int r = e >> 3, c8 = e & 7;
        stg8(wA, r, c8*8, &ff1_w[r*DM + c8*8], 128);
      }
    }
    for (int t = wid; t < 36; t += NW) {
      int mt = t / 6, nt = t - mt*6;
      int ar = mt*16 + l15, br = nt*16 + l15;
      short8 a = zfrag, w = zfrag;
      if (lane < 32) {
        a = *(const short8*)((const char*)qb + (h*96 + ar)*32 + kfr*2);
        w = *(const short8*)((const char*)kb + (h*96 + br)*32 + kfr*2);
      }
      f32x4 acc = {0.f,0.f,0.f,0.f};
      acc = __builtin_amdgcn_mfma_f32_16x16x32_bf16(a, w, acc, 0, 0, 0);
      int col = nt*16 + l15;
      #pragma unroll
      for (int i2 = 0; i2 < 4; ++i2)
        Sf[(mt*16 + mfr + i2)*SP + col] = acc[i2] * 0.25f;
    }
    __syncthreads();

    // A2: masked row softmax; P bf16 (unnormalized) aliases S rows; linv = 1/sum
    for (int i = wid; i < MR; i += NW) {
      float v0 = Sf[i*SP + lane];                       // cols 0..63
      bool has1 = (lane < 27);                          // cols 64..90
      float v1 = has1 ? Sf[i*SP + 64 + lane] : -3.0e38f;
      float m = fmaxf(v0, v1);
      #pragma unroll
      for (int off = 32; off >= 1; off >>= 1) m = fmaxf(m, __shfl_xor(m, off, 64));
      float e0 = __expf(v0 - m);
      float e1 = has1 ? __expf(v1 - m) : 0.f;
      float ssum = e0 + e1;
      #pragma unroll
      for (int off = 32; off >= 1; off >>= 1) ssum += __shfl_xor(ssum, off, 64);
      // store P (bf16, swizzled, 256B window inside 400B row)
      int c0 = lane;
      *(short*)((char*)r1f + i*400 + ((((c0>>3) ^ (i&7))<<4)) + ((c0&7)*2)) = f2bf(e0);
      if (lane < 32) {
        int c1 = 64 + lane;
        float ev = (lane < 27) ? e1 : 0.f;              // cols 91..95 forced 0
        *(short*)((char*)r1f + i*400 + ((((c1>>3) ^ (i&7))<<4)) + ((c1&7)*2)) = f2bf(ev);
      }
      if (lane == 0) linv[h*96 + i] = 1.0f / ssum;
    }
    __syncthreads();

    // A3: O = (P @ V) * linv  -> ab16 cols h*16..h*16+15
    for (int t = wid; t < 6; t += NW) {
      int ar = t*16 + l15;
      f32x4 acc = {0.f,0.f,0.f,0.f};
      #pragma unroll
      for (int kk = 0; kk < 3; ++kk) {
        int slot = kk*4 + (kfr >> 3);
        short8 a = *(const short8*)((const char*)r1f + ar*400 + ((slot ^ (ar&7)) << 4));
        short8 w = *(const short8*)((const char*)vtb + (h*16 + l15)*208 + kk*64 + kfr*2);
        acc = __builtin_amdgcn_mfma_f32_16x16x32_bf16(a, w, acc, 0, 0, 0);
      }
      #pragma unroll
      for (int i2 = 0; i2 < 4; ++i2) {
        int m = t*16 + mfr + i2;
        stb16_128(ab16, m, h*16 + l15, acc[i2] * linv[h*96 + m]);
      }
    }
    __syncthreads();
  }

  // ---- P5: out-proj MFMA: hbuf += o @ out_w^T + out_b ----
  for (int t = wid; t < 24; t += NW) {
    int mt = t >> 2, nt = t & 3;
    int ar = mt*16 + l15, br = nt*16 + l15;
    f32x4 acc = {0.f,0.f,0.f,0.f};
    #pragma unroll
    for (int kk = 0; kk < 2; ++kk) {
      short8 a = ldfrag128(ab16,       ar, kk*32 + kfr);
      short8 w = ldfrag128((short*)wB, br, kk*32 + kfr);
      acc = __builtin_amdgcn_mfma_f32_16x16x32_bf16(a, w, acc, 0, 0, 0);
    }
    int col = nt*16 + l15;
    float ob = out_b[col];
    #pragma unroll
    for (int i2 = 0; i2 < 4; ++i2) {
      int m = mt*16 + mfr + i2;
      hbuf[m*HP + col] += acc[i2] + ob;
    }
  }
  __syncthreads();

  // ---- P6: LN2 -> ab16 ; stage ff2 -> wB ----
  for (int e = tid; e < DM*CIN/8; e += NT) {      // ff2_w [64][128]
    int r = e >> 4, c8 = e & 15;
    stg8(wB, r, c8*8, &ff2_w[r*CIN + c8*8], 256);
  }
  {
    const float g = ln2_g[lane], bb = ln2_b[lane];
    for (int i = wid; i < NC; i += NW) {
      float v = hbuf[i*HP + lane];
      float s = v, sq = v*v;
      #pragma unroll
      for (int off = 32; off >= 1; off >>= 1) {
        s  += __shfl_xor(s, off, 64);
        sq += __shfl_xor(sq, off, 64);
      }
      float m  = s * (1.0f/64.0f);
      float vr = sq * (1.0f/64.0f) - m*m;
      float rs = rsqrtf(vr + 1e-5f);
      stb16_128(ab16, i, lane, (v - m) * rs * g + bb);
    }
  }
  __syncthreads();

  // ---- P7: ff1 MFMA (N=128, K=64) -> f1 bf16 in r2f ----
  short* f1 = (short*)r2f;                        // [96][128] bf16 swz PB=256
  for (int t = wid; t < 48; t += NW) {
    int mt = t >> 3, nt = t & 7;
    int ar = mt*16 + l15, br = nt*16 + l15;
    f32x4 acc = {0.f,0.f,0.f,0.f};
    #pragma unroll
    for (int kk = 0; kk < 2; ++kk) {
      short8 a = ldfrag128(ab16, ar, kk*32 + kfr);
      short8 w = ldfrag128(wA,   br, kk*32 + kfr);
      acc = __builtin_amdgcn_mfma_f32_16x16x32_bf16(a, w, acc, 0, 0, 0);
    }
    int col = nt*16 + l15;
    float bia = ff1_b[col];
    #pragma unroll
    for (int i2 = 0; i2 < 4; ++i2) {
      int m = mt*16 + mfr + i2;
      *(short*)((char*)f1 + SWZ(m, col, 256)) = f2bf(fmaxf(acc[i2] + bia, 0.f));
    }
  }
  __syncthreads();

  // ---- P8: ff2 MFMA (K=128): ab16 = bf16(hbuf + f1@W^T + b) ; stage from/to -> wA ----
  for (int e = tid; e < 2*DM*DM/8; e += NT) {     // [128][64]: rows 0..63 from, 64..127 to
    int r = e >> 3, c8 = e & 7;
    const float* src = (r < DM) ? &from_w[r*DM + c8*8] : &to_w[(r-DM)*DM + c8*8];
    stg8(wA, r, c8*8, src, 128);
  }
  for (int t = wid; t < 24; t += NW) {
    int mt = t >> 2, nt = t & 3;
    int ar = mt*16 + l15, br = nt*16 + l15;
    f32x4 acc = {0.f,0.f,0.f,0.f};
    #pragma unroll
    for (int kk = 0; kk < 4; ++kk) {
      short8 a = ldfrag256(f1, ar, kk*32 + kfr);
      short8 w = ldfrag256(wB, br, kk*32 + kfr);
      acc = __builtin_amdgcn_mfma_f32_16x16x32_bf16(a, w, acc, 0, 0, 0);
    }
    int col = nt*16 + l15;
    float bia = ff2_b[col];
    #pragma unroll
    for (int i2 = 0; i2 < 4; ++i2) {
      int m = mt*16 + mfr + i2;
      stb16_128(ab16, m, col, hbuf[m*HP + col] + acc[i2] + bia);
    }
  }
  __syncthreads();

  // ---- P9: from/to MFMA (N=128, K=64) -> F, T bf16 in r2f ----
  short* Fb = (short*)r2f;                        // [96][64] bf16 swz PB=128
  short* Tb = (short*)r2f + 6144;
  for (int t = wid; t < 48; t += NW) {
    int mt = t >> 3, nt = t & 7;
    int ar = mt*16 + l15, br = nt*16 + l15;
    f32x4 acc = {0.f,0.f,0.f,0.f};
    #pragma unroll
    for (int kk = 0; kk < 2; ++kk) {
      short8 a = ldfrag128(ab16, ar, kk*32 + kfr);
      short8 w = ldfrag128(wA,   br, kk*32 + kfr);
      acc = __builtin_amdgcn_mfma_f32_16x16x32_bf16(a, w, acc, 0, 0, 0);
    }
    int col = nt*16 + l15;
    if (nt < 4) {
      float bia = from_b[col];
      #pragma unroll
      for (int i2 = 0; i2 < 4; ++i2)
        stb16_128(Fb, mt*16 + mfr + i2, col, acc[i2] + bia);
    } else {
      int c2 = col - 64;
      float bia = to_b[c2];
      #pragma unroll
      for (int i2 = 0; i2 < 4; ++i2)
        stb16_128(Tb, mt*16 + mfr + i2, c2, acc[i2] + bia);
    }
  }
  __syncthreads();

  // ---- P10: gram MFMA: G = F @ T^T (96x96, K=64) -> r1f ----
  float* G = r1f;
  for (int t = wid; t < 36; t += NW) {
    int mt = t / 6, nt = t - mt*6;
    int ar = mt*16 + l15, br = nt*16 + l15;
    f32x4 acc = {0.f,0.f,0.f,0.f};
    #pragma unroll
    for (int kk = 0; kk < 2; ++kk) {
      short8 a = ldfrag128(Fb, ar, kk*32 + kfr);
      short8 w = ldfrag128(Tb, br, kk*32 + kfr);
      acc = __builtin_amdgcn_mfma_f32_16x16x32_bf16(a, w, acc, 0, 0, 0);
    }
    int col = nt*16 + l15;
    #pragma unroll
    for (int i2 = 0; i2 < 4; ++i2)
      G[(mt*16 + mfr + i2)*GP + col] = acc[i2];
  }
  __syncthreads();

  // ---- P11: logits gather ----
  {
    float* ob = out + (size_t)b * NMOV;
    for (int m = tid; m < NMOV; m += NT) {
      ob[m] = G[move_from[m]*GP + move_to[m]] + move_bias[m];
    }
  }
}

extern "C" void kernel_launch(void* const* d_in, const int* in_sizes, int n_in,
                              void* d_out, int out_size, void* d_ws, size_t ws_size,
                              hipStream_t stream) {
  const float* x        = (const float*)d_in[0];
  const float* embed_w  = (const float*)d_in[1];
  const float* embed_b  = (const float*)d_in[2];
  const float* pos      = (const float*)d_in[3];
  const float* in_w     = (const float*)d_in[4];
  const float* in_b     = (const float*)d_in[5];
  const float* out_w    = (const float*)d_in[6];
  const float* out_b    = (const float*)d_in[7];
  const float* ln1_g    = (const float*)d_in[8];
  const float* ln1_b    = (const float*)d_in[9];
  const float* ln2_g    = (const float*)d_in[10];
  const float* ln2_b    = (const float*)d_in[11];
  const float* ff1_w    = (const float*)d_in[12];
  const float* ff1_b    = (const float*)d_in[13];
  const float* ff2_w    = (const float*)d_in[14];
  const float* ff2_b    = (const float*)d_in[15];
  const float* from_w   = (const float*)d_in[16];
  const float* from_b   = (const float*)d_in[17];
  const float* to_w     = (const float*)d_in[18];
  const float* to_b     = (const float*)d_in[19];
  const float* move_bias= (const float*)d_in[20];
  const int*   move_from= (const int*)d_in[21];
  const int*   move_to  = (const int*)d_in[22];

  int B = in_sizes[0] / (CIN * 121);
  policy_fused<<<dim3(B), dim3(NT), 0, stream>>>(
      x, embed_w, embed_b, pos, in_w, in_b, out_w, out_b,
      ln1_g, ln1_b, ln2_g, ln2_b, ff1_w, ff1_b, ff2_w, ff2_b,
      from_w, from_b, to_w, to_b, move_bias, move_from, move_to,
      (float*)d_out);
}

// Round 8
// 58.092 us; speedup vs baseline: 1.4870x; 1.4870x over previous
//
#include <hip/hip_runtime.h>
#include <hip/hip_bf16.h>

typedef __attribute__((ext_vector_type(8))) short short8;
typedef __attribute__((ext_vector_type(4))) float f32x4;

#define NC    91
#define DM    64
#define CIN   128
#define NMOV  4206
#define MR    96      // row-padded (6 x 16)
#define HP    68      // hbuf fp32 pitch
#define QP    196     // qkv fp32 pitch
#define GP    96      // gram fp32 pitch
#define NT    1024
#define NW    16

__constant__ int HEXOFF[NC] = {
  55,66,77,88,99,110,
  45,56,67,78,89,100,111,
  35,46,57,68,79,90,101,112,
  25,36,47,58,69,80,91,102,113,
  15,26,37,48,59,70,81,92,103,114,
  5,16,27,38,49,60,71,82,93,104,115,
  6,17,28,39,50,61,72,83,94,105,
  7,18,29,40,51,62,73,84,95,
  8,19,30,41,52,63,74,85,
  9,20,31,42,53,64,75,
  10,21,32,43,54,65
};

// byte offset into a bf16 buffer with PB bytes/row; 16B-slot XOR swizzle by row&7
#define SWZ(row, col, PB) ((row)*(PB) + ((((((col)*2)>>4)) ^ ((row)&7)) << 4) + (((col)*2)&15))

__device__ __forceinline__ short f2bf(float f) {
  __hip_bfloat16 h = __float2bfloat16(f);
  return __builtin_bit_cast(short, h);
}

__device__ __forceinline__ short8 ldfrag128(const short* buf, int row, int k0) {
  return *(const short8*)((const char*)buf + SWZ(row, k0, 128));
}
__device__ __forceinline__ short8 ldfrag256(const short* buf, int row, int k0) {
  return *(const short8*)((const char*)buf + SWZ(row, k0, 256));
}
__device__ __forceinline__ void stb16_128(short* buf, int row, int col, float v) {
  *(short*)((char*)buf + SWZ(row, col, 128)) = f2bf(v);
}

// stage 8 consecutive floats (col multiple of 8) as one swizzled 16B bf16 store
__device__ __forceinline__ void stg8(short* buf, int row, int col, const float* src, int PB) {
  float4 f0 = *(const float4*)(src);
  float4 f1 = *(const float4*)(src + 4);
  short8 v;
  v[0]=f2bf(f0.x); v[1]=f2bf(f0.y); v[2]=f2bf(f0.z); v[3]=f2bf(f0.w);
  v[4]=f2bf(f1.x); v[5]=f2bf(f1.y); v[6]=f2bf(f1.z); v[7]=f2bf(f1.w);
  *(short8*)((char*)buf + (row)*(PB) + (((((col)*2)>>4) ^ ((row)&7)) << 4)) = v;
}

// 16-lane-group LayerNorm: rows i=g*4+sub, cols l16*4..+3, writes bf16 to ab16 (swz PB=128)
__device__ __forceinline__ void ln_group(const float* hbuf, short* ab16,
                                         const float* gw, const float* gb,
                                         int wid, int lane) {
  const int sub = lane >> 4;
  const int l16 = lane & 15;
  const float4 g4 = *(const float4*)&gw[l16*4];
  const float4 b4 = *(const float4*)&gb[l16*4];
  for (int g = wid; g < 23; g += NW) {
    int i = g*4 + sub;
    if (i < NC) {
      float4 v = *(const float4*)&hbuf[i*HP + l16*4];
      float s  = (v.x + v.y) + (v.z + v.w);
      float sq = fmaf(v.x,v.x, fmaf(v.y,v.y, fmaf(v.z,v.z, v.w*v.w)));
      #pragma unroll
      for (int off = 1; off < 16; off <<= 1) {
        s  += __shfl_xor(s, off, 64);
        sq += __shfl_xor(sq, off, 64);
      }
      float m  = s * (1.0f/64.0f);
      float vr = sq * (1.0f/64.0f) - m*m;
      float rs = rsqrtf(vr + 1e-5f);
      short4 o;
      o.x = f2bf((v.x - m)*rs*g4.x + b4.x);
      o.y = f2bf((v.y - m)*rs*g4.y + b4.y);
      o.z = f2bf((v.z - m)*rs*g4.z + b4.z);
      o.w = f2bf((v.w - m)*rs*g4.w + b4.w);
      *(short4*)((char*)ab16 + i*128 + (((l16>>1) ^ (i&7))<<4) + (l16&1)*8) = o;
    }
  }
}

__global__ __launch_bounds__(1024, 1)
void policy_fused(
    const float* __restrict__ x,
    const float* __restrict__ embed_w, const float* __restrict__ embed_b,
    const float* __restrict__ pos,
    const float* __restrict__ in_w,  const float* __restrict__ in_b,
    const float* __restrict__ out_w, const float* __restrict__ out_b,
    const float* __restrict__ ln1_g, const float* __restrict__ ln1_b,
    const float* __restrict__ ln2_g, const float* __restrict__ ln2_b,
    const float* __restrict__ ff1_w, const float* __restrict__ ff1_b,
    const float* __restrict__ ff2_w, const float* __restrict__ ff2_b,
    const float* __restrict__ from_w, const float* __restrict__ from_b,
    const float* __restrict__ to_w,  const float* __restrict__ to_b,
    const float* __restrict__ move_bias,
    const int* __restrict__ move_from, const int* __restrict__ move_to,
    float* __restrict__ out)
{
  __shared__ float hbuf[MR*HP];      // residual h fp32               26112 B
  __shared__ float arena[18816];     // feats16/qkv/f1/F,T,G          75264 B
  __shared__ short ab16[MR*64];      // bf16 A-staging (swz, PB=128)  12288 B
  __shared__ short wA[192*64];       // weights bf16 (swz, PB=128)    24576 B
  __shared__ short wB[64*128];       // weights bf16 (swz, PB=256)    16384 B

  const int tid  = threadIdx.x;
  const int lane = tid & 63;
  const int wid  = tid >> 6;
  const int l15  = lane & 15;
  const int kfr  = (lane >> 4) * 8;   // k offset within a 32-wide k-chunk
  const int mfr  = (lane >> 4) * 4;   // C-frag row offset
  const int b    = blockIdx.x;
  const float* xb = x + (size_t)b * (CIN*121);

  // ---- P0: hex-gather feats -> bf16 arena ; stage embed_w -> wB ----
  short* featsb = (short*)arena;                 // [96][128] bf16 swz PB=256
  for (int e = tid; e < 16*NC; e += NT) {        // 8 channels per item
    int c0 = e / NC, i = e - c0*NC;
    float v[8];
    #pragma unroll
    for (int u = 0; u < 8; ++u) v[u] = xb[(c0*8 + u)*121 + HEXOFF[i]];
    short8 s8;
    #pragma unroll
    for (int u = 0; u < 8; ++u) s8[u] = f2bf(v[u]);
    *(short8*)((char*)featsb + i*256 + ((c0 ^ (i&7)) << 4)) = s8;
  }
  for (int e = tid; e < DM*CIN/8; e += NT) {     // embed_w [64][128]
    int r = e >> 4, c8 = e & 15;
    stg8(wB, r, c8*8, &embed_w[r*CIN + c8*8], 256);
  }
  __syncthreads();

  // ---- P1: embed MFMA (K=128) -> hbuf fp32 ; stage in_w -> wA ----
  for (int e = tid; e < 3*DM*DM/8; e += NT) {    // in_w [192][64]
    int r = e >> 3, c8 = e & 7;
    stg8(wA, r, c8*8, &in_w[r*DM + c8*8], 128);
  }
  for (int t = wid; t < 24; t += NW) {
    int mt = t >> 2, nt = t & 3;
    int ar = mt*16 + l15, br = nt*16 + l15;
    f32x4 acc = {0.f,0.f,0.f,0.f};
    #pragma unroll
    for (int kk = 0; kk < 4; ++kk) {
      short8 a = ldfrag256(featsb, ar, kk*32 + kfr);
      short8 w = ldfrag256(wB,      br, kk*32 + kfr);
      acc = __builtin_amdgcn_mfma_f32_16x16x32_bf16(a, w, acc, 0, 0, 0);
    }
    int col = nt*16 + l15;
    float eb = embed_b[col];
    #pragma unroll
    for (int i2 = 0; i2 < 4; ++i2) {
      int m = mt*16 + mfr + i2;
      float p = (m < NC) ? pos[m*DM + col] : 0.f;
      hbuf[m*HP + col] = acc[i2] + eb + p;
    }
  }
  __syncthreads();

  // ---- P2: LN1 -> ab16 bf16 ; stage out_w -> wB(PB=128 region) ----
  for (int e = tid; e < DM*DM/8; e += NT) {
    int r = e >> 3, c8 = e & 7;
    stg8((short*)wB, r, c8*8, &out_w[r*DM + c8*8], 128);
  }
  if (tid < 160) ((unsigned*)ab16)[2912 + tid] = 0;     // zero ab16 rows 91..95
  ln_group(hbuf, ab16, ln1_g, ln1_b, wid, lane);
  __syncthreads();

  // ---- P3: qkv MFMA (N=192, K=64) -> qkv fp32 in arena ----
  float* qkv = arena;                             // [96][196] fp32
  for (int t = wid; t < 72; t += NW) {
    int mt = t / 12, nt = t - mt*12;
    int ar = mt*16 + l15, br = nt*16 + l15;
    f32x4 acc = {0.f,0.f,0.f,0.f};
    #pragma unroll
    for (int kk = 0; kk < 2; ++kk) {
      short8 a = ldfrag128(ab16, ar, kk*32 + kfr);
      short8 w = ldfrag128(wA,   br, kk*32 + kfr);
      acc = __builtin_amdgcn_mfma_f32_16x16x32_bf16(a, w, acc, 0, 0, 0);
    }
    int col = nt*16 + l15;
    float bia = in_b[col];
    #pragma unroll
    for (int i2 = 0; i2 < 4; ++i2)
      qkv[(mt*16 + mfr + i2)*QP + col] = acc[i2] + bia;
  }
  __syncthreads();

  // ---- P4: attention (2 threads per (h,i), 728 active) ; stage ff1 -> wA ----
  for (int e = tid; e < 2*DM*DM/8; e += NT) {     // ff1_w [128][64]
    int r = e >> 3, c8 = e & 7;
    stg8(wA, r, c8*8, &ff1_w[r*DM + c8*8], 128);
  }
  {
    const int q2   = tid >> 1;
    const int half = tid & 1;
    if (q2 < 4*NC) {
      const int h = q2 / NC;
      const int i = q2 - h*NC;
      const float CS = 0.25f * 1.4426950408889634f;   // fold scale*log2e into q
      const float* qr = &qkv[i*QP + h*16];
      float4 qa = *(const float4*)(qr+0),  qb = *(const float4*)(qr+4),
             qc = *(const float4*)(qr+8),  qd = *(const float4*)(qr+12);
      qa.x*=CS; qa.y*=CS; qa.z*=CS; qa.w*=CS;
      qb.x*=CS; qb.y*=CS; qb.z*=CS; qb.w*=CS;
      qc.x*=CS; qc.y*=CS; qc.z*=CS; qc.w*=CS;
      qd.x*=CS; qd.y*=CS; qd.z*=CS; qd.w*=CS;
      float4 oa = {0,0,0,0}, obv = {0,0,0,0}, ocv = {0,0,0,0}, odv = {0,0,0,0};
      float lrun = 0.0f;
      const int j0 = half ? 46 : 0;
      const int j1 = half ? NC : 46;
      for (int j = j0; j < j1; ++j) {
        const float* kr = &qkv[j*QP + DM + h*16];
        float4 ka = *(const float4*)(kr+0), kb = *(const float4*)(kr+4),
               kc = *(const float4*)(kr+8), kd = *(const float4*)(kr+12);
        float t0 = fmaf(qa.w,ka.w, fmaf(qa.z,ka.z, fmaf(qa.y,ka.y, qa.x*ka.x)));
        float t1 = fmaf(qb.w,kb.w, fmaf(qb.z,kb.z, fmaf(qb.y,kb.y, qb.x*kb.x)));
        float t2 = fmaf(qc.w,kc.w, fmaf(qc.z,kc.z, fmaf(qc.y,kc.y, qc.x*kc.x)));
        float t3 = fmaf(qd.w,kd.w, fmaf(qd.z,kd.z, fmaf(qd.y,kd.y, qd.x*kd.x)));
        float s2 = (t0+t1)+(t2+t3);               // already scaled to log2 domain
        float pw = exp2f(s2);                     // no-max softmax (|s| small, safe)
        lrun += pw;
        const float* vr = &qkv[j*QP + 2*DM + h*16];
        float4 va = *(const float4*)(vr+0), vb = *(const float4*)(vr+4),
               vc = *(const float4*)(vr+8), vd = *(const float4*)(vr+12);
        oa.x  = fmaf(pw, va.x, oa.x);  oa.y  = fmaf(pw, va.y, oa.y);
        oa.z  = fmaf(pw, va.z, oa.z);  oa.w  = fmaf(pw, va.w, oa.w);
        obv.x = fmaf(pw, vb.x, obv.x); obv.y = fmaf(pw, vb.y, obv.y);
        obv.z = fmaf(pw, vb.z, obv.z); obv.w = fmaf(pw, vb.w, obv.w);
        ocv.x = fmaf(pw, vc.x, ocv.x); ocv.y = fmaf(pw, vc.y, ocv.y);
        ocv.z = fmaf(pw, vc.z, ocv.z); ocv.w = fmaf(pw, vc.w, ocv.w);
        odv.x = fmaf(pw, vd.x, odv.x); odv.y = fmaf(pw, vd.y, odv.y);
        odv.z = fmaf(pw, vd.z, odv.z); odv.w = fmaf(pw, vd.w, odv.w);
      }
      // merge the two halves (adjacent lanes): plain sums
      lrun += __shfl_xor(lrun, 1, 64);
      #define MRG(c) c += __shfl_xor(c, 1, 64)
      MRG(oa.x); MRG(oa.y); MRG(oa.z); MRG(oa.w);
      MRG(obv.x); MRG(obv.y); MRG(obv.z); MRG(obv.w);
      MRG(ocv.x); MRG(ocv.y); MRG(ocv.z); MRG(ocv.w);
      MRG(odv.x); MRG(odv.y); MRG(odv.z); MRG(odv.w);
      #undef MRG
      float inv = 1.0f / lrun;
      float4 w0 = half ? ocv : oa;
      float4 w1 = half ? odv : obv;
      short8 ow;
      ow[0]=f2bf(w0.x*inv); ow[1]=f2bf(w0.y*inv); ow[2]=f2bf(w0.z*inv); ow[3]=f2bf(w0.w*inv);
      ow[4]=f2bf(w1.x*inv); ow[5]=f2bf(w1.y*inv); ow[6]=f2bf(w1.z*inv); ow[7]=f2bf(w1.w*inv);
      *(short8*)((char*)ab16 + SWZ(i, h*16 + half*8, 128)) = ow;
    }
  }
  __syncthreads();

  // ---- P5: out-proj MFMA: hbuf += o @ out_w^T + out_b ----
  for (int t = wid; t < 24; t += NW) {
    int mt = t >> 2, nt = t & 3;
    int ar = mt*16 + l15, br = nt*16 + l15;
    f32x4 acc = {0.f,0.f,0.f,0.f};
    #pragma unroll
    for (int kk = 0; kk < 2; ++kk) {
      short8 a = ldfrag128(ab16,       ar, kk*32 + kfr);
      short8 w = ldfrag128((short*)wB, br, kk*32 + kfr);
      acc = __builtin_amdgcn_mfma_f32_16x16x32_bf16(a, w, acc, 0, 0, 0);
    }
    int col = nt*16 + l15;
    float ob = out_b[col];
    #pragma unroll
    for (int i2 = 0; i2 < 4; ++i2) {
      int m = mt*16 + mfr + i2;
      hbuf[m*HP + col] += acc[i2] + ob;
    }
  }
  __syncthreads();

  // ---- P6: LN2 -> ab16 ; stage ff2 -> wB ----
  for (int e = tid; e < DM*CIN/8; e += NT) {      // ff2_w [64][128]
    int r = e >> 4, c8 = e & 15;
    stg8(wB, r, c8*8, &ff2_w[r*CIN + c8*8], 256);
  }
  ln_group(hbuf, ab16, ln2_g, ln2_b, wid, lane);
  __syncthreads();

  // ---- P7: ff1 MFMA (N=128, K=64) -> f1 bf16 in arena ----
  short* f1 = (short*)arena;                      // [96][128] bf16 swz PB=256
  for (int t = wid; t < 48; t += NW) {
    int mt = t >> 3, nt = t & 7;
    int ar = mt*16 + l15, br = nt*16 + l15;
    f32x4 acc = {0.f,0.f,0.f,0.f};
    #pragma unroll
    for (int kk = 0; kk < 2; ++kk) {
      short8 a = ldfrag128(ab16, ar, kk*32 + kfr);
      short8 w = ldfrag128(wA,   br, kk*32 + kfr);
      acc = __builtin_amdgcn_mfma_f32_16x16x32_bf16(a, w, acc, 0, 0, 0);
    }
    int col = nt*16 + l15;
    float bia = ff1_b[col];
    #pragma unroll
    for (int i2 = 0; i2 < 4; ++i2) {
      int m = mt*16 + mfr + i2;
      *(short*)((char*)f1 + SWZ(m, col, 256)) = f2bf(fmaxf(acc[i2] + bia, 0.f));
    }
  }
  __syncthreads();

  // ---- P8: ff2 MFMA (K=128): ab16 = bf16(hbuf + f1@W^T + b) ; stage from/to -> wA ----
  for (int e = tid; e < 2*DM*DM/8; e += NT) {     // [128][64]: rows 0..63 from, 64..127 to
    int r = e >> 3, c8 = e & 7;
    const float* src = (r < DM) ? &from_w[r*DM + c8*8] : &to_w[(r-DM)*DM + c8*8];
    stg8(wA, r, c8*8, src, 128);
  }
  for (int t = wid; t < 24; t += NW) {
    int mt = t >> 2, nt = t & 3;
    int ar = mt*16 + l15, br = nt*16 + l15;
    f32x4 acc = {0.f,0.f,0.f,0.f};
    #pragma unroll
    for (int kk = 0; kk < 4; ++kk) {
      short8 a = ldfrag256(f1, ar, kk*32 + kfr);
      short8 w = ldfrag256(wB, br, kk*32 + kfr);
      acc = __builtin_amdgcn_mfma_f32_16x16x32_bf16(a, w, acc, 0, 0, 0);
    }
    int col = nt*16 + l15;
    float bia = ff2_b[col];
    #pragma unroll
    for (int i2 = 0; i2 < 4; ++i2) {
      int m = mt*16 + mfr + i2;
      stb16_128(ab16, m, col, hbuf[m*HP + col] + acc[i2] + bia);
    }
  }
  __syncthreads();

  // ---- P9: from/to MFMA (N=128, K=64) -> F, T bf16 ----
  short* Fb = (short*)arena;                      // [96][64] bf16 swz PB=128
  short* Tb = (short*)arena + 6144;               // [96][64] bf16 swz PB=128
  for (int t = wid; t < 48; t += NW) {
    int mt = t >> 3, nt = t & 7;
    int ar = mt*16 + l15, br = nt*16 + l15;
    f32x4 acc = {0.f,0.f,0.f,0.f};
    #pragma unroll
    for (int kk = 0; kk < 2; ++kk) {
      short8 a = ldfrag128(ab16, ar, kk*32 + kfr);
      short8 w = ldfrag128(wA,   br, kk*32 + kfr);
      acc = __builtin_amdgcn_mfma_f32_16x16x32_bf16(a, w, acc, 0, 0, 0);
    }
    int col = nt*16 + l15;
    if (nt < 4) {
      float bia = from_b[col];
      #pragma unroll
      for (int i2 = 0; i2 < 4; ++i2)
        stb16_128(Fb, mt*16 + mfr + i2, col, acc[i2] + bia);
    } else {
      int c2 = col - 64;
      float bia = to_b[c2];
      #pragma unroll
      for (int i2 = 0; i2 < 4; ++i2)
        stb16_128(Tb, mt*16 + mfr + i2, c2, acc[i2] + bia);
    }
  }
  __syncthreads();

  // ---- P10: gram MFMA: G = F @ T^T (96x96, K=64) ----
  float* G = arena + 6144;                        // [96][96] fp32
  for (int t = wid; t < 36; t += NW) {
    int mt = t / 6, nt = t - mt*6;
    int ar = mt*16 + l15, br = nt*16 + l15;
    f32x4 acc = {0.f,0.f,0.f,0.f};
    #pragma unroll
    for (int kk = 0; kk < 2; ++kk) {
      short8 a = ldfrag128(Fb, ar, kk*32 + kfr);
      short8 w = ldfrag128(Tb, br, kk*32 + kfr);
      acc = __builtin_amdgcn_mfma_f32_16x16x32_bf16(a, w, acc, 0, 0, 0);
    }
    int col = nt*16 + l15;
    #pragma unroll
    for (int i2 = 0; i2 < 4; ++i2)
      G[(mt*16 + mfr + i2)*GP + col] = acc[i2];
  }
  __syncthreads();

  // ---- P11: logits gather ----
  {
    float* ob = out + (size_t)b * NMOV;
    for (int m = tid; m < NMOV; m += NT) {
      ob[m] = G[move_from[m]*GP + move_to[m]] + move_bias[m];
    }
  }
}

extern "C" void kernel_launch(void* const* d_in, const int* in_sizes, int n_in,
                              void* d_out, int out_size, void* d_ws, size_t ws_size,
                              hipStream_t stream) {
  const float* x        = (const float*)d_in[0];
  const float* embed_w  = (const float*)d_in[1];
  const float* embed_b  = (const float*)d_in[2];
  const float* pos      = (const float*)d_in[3];
  const float* in_w     = (const float*)d_in[4];
  const float* in_b     = (const float*)d_in[5];
  const float* out_w    = (const float*)d_in[6];
  const float* out_b    = (const float*)d_in[7];
  const float* ln1_g    = (const float*)d_in[8];
  const float* ln1_b    = (const float*)d_in[9];
  const float* ln2_g    = (const float*)d_in[10];
  const float* ln2_b    = (const float*)d_in[11];
  const float* ff1_w    = (const float*)d_in[12];
  const float* ff1_b    = (const float*)d_in[13];
  const float* ff2_w    = (const float*)d_in[14];
  const float* ff2_b    = (const float*)d_in[15];
  const float* from_w   = (const float*)d_in[16];
  const float* from_b   = (const float*)d_in[17];
  const float* to_w     = (const float*)d_in[18];
  const float* to_b     = (const float*)d_in[19];
  const float* move_bias= (const float*)d_in[20];
  const int*   move_from= (const int*)d_in[21];
  const int*   move_to  = (const int*)d_in[22];

  int B = in_sizes[0] / (CIN * 121);
  policy_fused<<<dim3(B), dim3(NT), 0, stream>>>(
      x, embed_w, embed_b, pos, in_w, in_b, out_w, out_b,
      ln1_g, ln1_b, ln2_g, ln2_b, ff1_w, ff1_b, ff2_w, ff2_b,
      from_w, from_b, to_w, to_b, move_bias, move_from, move_to,
      (float*)d_out);
}